// Round 3
// baseline (27.157 us; speedup 1.0000x reference)
//
#include <hip/hip_runtime.h>

// B-spline (degree 3, 16 control points, uniform knots linspace(-3,3,20)).
// out(x) = cubic polynomial in u, coefficients per interval j = floor((x+3)/h),
// c(j) a fixed linear combo of cp[j-3..j] (out-of-range cp -> 0).
// x < -3 or x >= 3 -> 0 (matches the reference recursion incl. x==3 edge).

#define N_CP   16
#define NINT   19          // knots = linspace(-3,3,20) -> 19 intervals
#define TPB    256
#define UNROLL 8

typedef float f32x4 __attribute__((ext_vector_type(4)));  // native vec: ok for nontemporal builtins

__device__ __forceinline__ float eval_one(float xe, const f32x4* sc) {
    const float inv_h = (float)NINT / 6.0f;
    float t = (xe + 3.0f) * inv_h;                   // knot-index space
    bool in_range = (t >= 0.0f) & (t < (float)NINT); // NaN-safe: false
    float fj = floorf(t);
    int j = (int)fj;
    j = j < 0 ? 0 : (j > NINT - 1 ? NINT - 1 : j);
    float u = t - fj;
    f32x4 c = sc[j];                                 // ds_read_b128
    float res = ((c.w * u + c.z) * u + c.y) * u + c.x;
    return in_range ? res : 0.0f;
}

__device__ __forceinline__ void build_coefs(const float* __restrict__ cp,
                                            f32x4* sc) {
    int tid = threadIdx.x;
    if (tid < NINT) {
        int j = tid;
        float p0 = (j - 3 >= 0 && j - 3 < N_CP) ? cp[j - 3] : 0.0f;
        float p1 = (j - 2 >= 0 && j - 2 < N_CP) ? cp[j - 2] : 0.0f;
        float p2 = (j - 1 >= 0 && j - 1 < N_CP) ? cp[j - 1] : 0.0f;
        float p3 = (j     < N_CP)               ? cp[j]     : 0.0f;
        // uniform cubic B-spline basis in powers of u
        f32x4 c;
        c.x = (p0 + 4.0f * p1 + p2) * (1.0f / 6.0f);
        c.y = (p2 - p0) * 0.5f;
        c.z = (p0 - 2.0f * p1 + p2) * 0.5f;
        c.w = (p3 - p0) * (1.0f / 6.0f) + (p1 - p2) * 0.5f;
        sc[j] = c;
    }
}

__global__ __launch_bounds__(TPB) void bspline_kernel(
    const float* __restrict__ x,
    const float* __restrict__ cp,
    float* __restrict__ out,
    int n)
{
    __shared__ f32x4 sc[NINT];
    build_coefs(cp, sc);
    __syncthreads();

    int n4 = n >> 2;
    const f32x4* x4 = (const f32x4*)x;
    f32x4* o4 = (f32x4*)out;

    int tid = threadIdx.x;
    int base = blockIdx.x * (TPB * UNROLL) + tid;

    if (base + (UNROLL - 1) * TPB < n4) {
        // fast path: issue all 8 coalesced 16B loads, then compute+store
        f32x4 v[UNROLL];
#pragma unroll
        for (int k = 0; k < UNROLL; ++k)
            v[k] = __builtin_nontemporal_load(&x4[base + k * TPB]);
#pragma unroll
        for (int k = 0; k < UNROLL; ++k) {
            f32x4 r;
            r.x = eval_one(v[k].x, sc);
            r.y = eval_one(v[k].y, sc);
            r.z = eval_one(v[k].z, sc);
            r.w = eval_one(v[k].w, sc);
            __builtin_nontemporal_store(r, &o4[base + k * TPB]);
        }
    } else {
        // guarded tail blocks
#pragma unroll
        for (int k = 0; k < UNROLL; ++k) {
            int i = base + k * TPB;
            if (i < n4) {
                f32x4 v = x4[i];
                f32x4 r;
                r.x = eval_one(v.x, sc);
                r.y = eval_one(v.y, sc);
                r.z = eval_one(v.z, sc);
                r.w = eval_one(v.w, sc);
                o4[i] = r;
            }
        }
    }

    // scalar tail (n not multiple of 4)
    int g = blockIdx.x * TPB + tid;
    int gs = gridDim.x * TPB;
    for (int i = (n4 << 2) + g; i < n; i += gs)
        out[i] = eval_one(x[i], sc);
}

extern "C" void kernel_launch(void* const* d_in, const int* in_sizes, int n_in,
                              void* d_out, int out_size, void* d_ws, size_t ws_size,
                              hipStream_t stream) {
    const float* x  = (const float*)d_in[0];
    const float* cp = (const float*)d_in[1];
    float* out = (float*)d_out;

    int n = in_sizes[0];
    int n4 = n >> 2;
    int per_block = TPB * UNROLL;
    int blocks = (n4 + per_block - 1) / per_block;
    if (blocks < 1) blocks = 1;

    bspline_kernel<<<blocks, TPB, 0, stream>>>(x, cp, out, n);
}

// Round 4
// 25.489 us; speedup vs baseline: 1.0654x; 1.0654x over previous
//
#include <hip/hip_runtime.h>

// B-spline (degree 3, 16 control points, uniform knots linspace(-3,3,20)).
// out(x) = cubic polynomial in u, coefficients per interval j = floor((x+3)/h).
// Zero-padded coef table: index jc = clamp(j+1, 0, 20); entries 0 and 20 hold
// zero polynomials, so out-of-range x (x < -3, x >= 3 incl. ==3) yields 0
// without an explicit range check. Matches the reference recursion.

#define N_CP   16
#define NINT   19          // knots = linspace(-3,3,20) -> 19 intervals
#define NTAB   (NINT + 2)  // 21: zero guard entries at both ends
#define TPB    256
#define UNROLL 8

typedef float f32x4 __attribute__((ext_vector_type(4)));

__device__ __forceinline__ float eval_one(float xe, const f32x4* sc) {
    const float inv_h = (float)NINT / 6.0f;
    float t = (xe + 3.0f) * inv_h;                   // knot-index space
    float fj = floorf(t);
    int jc = (int)fj + 1;                            // table index (+1 for guard)
    jc = jc < 0 ? 0 : (jc > NTAB - 1 ? NTAB - 1 : jc);
    float u = t - fj;                                // finite garbage ok on guards
    f32x4 c = sc[jc];                                // ds_read_b128
    return ((c.w * u + c.z) * u + c.y) * u + c.x;    // zero coefs -> 0
}

__device__ __forceinline__ void build_coefs(const float* __restrict__ cp,
                                            f32x4* sc) {
    int tid = threadIdx.x;
    if (tid < NTAB) {
        f32x4 c = {0.0f, 0.0f, 0.0f, 0.0f};
        if (tid >= 1 && tid <= NINT) {
            int j = tid - 1;                          // real interval index
            float p0 = (j - 3 >= 0 && j - 3 < N_CP) ? cp[j - 3] : 0.0f;
            float p1 = (j - 2 >= 0 && j - 2 < N_CP) ? cp[j - 2] : 0.0f;
            float p2 = (j - 1 >= 0 && j - 1 < N_CP) ? cp[j - 1] : 0.0f;
            float p3 = (j     < N_CP)               ? cp[j]     : 0.0f;
            // uniform cubic B-spline basis in powers of u
            c.x = (p0 + 4.0f * p1 + p2) * (1.0f / 6.0f);
            c.y = (p2 - p0) * 0.5f;
            c.z = (p0 - 2.0f * p1 + p2) * 0.5f;
            c.w = (p3 - p0) * (1.0f / 6.0f) + (p1 - p2) * 0.5f;
        }
        sc[tid] = c;
    }
}

__global__ __launch_bounds__(TPB) void bspline_kernel(
    const float* __restrict__ x,
    const float* __restrict__ cp,
    float* __restrict__ out,
    int n)
{
    __shared__ f32x4 sc[NTAB];
    build_coefs(cp, sc);
    __syncthreads();

    int n4 = n >> 2;
    const f32x4* x4 = (const f32x4*)x;
    f32x4* o4 = (f32x4*)out;

    int tid = threadIdx.x;
    int base = blockIdx.x * (TPB * UNROLL) + tid;

    if (base + (UNROLL - 1) * TPB < n4) {
        // fast path: issue all 8 coalesced 16B loads, then compute+store
        f32x4 v[UNROLL];
#pragma unroll
        for (int k = 0; k < UNROLL; ++k)
            v[k] = x4[base + k * TPB];
#pragma unroll
        for (int k = 0; k < UNROLL; ++k) {
            f32x4 r;
            r.x = eval_one(v[k].x, sc);
            r.y = eval_one(v[k].y, sc);
            r.z = eval_one(v[k].z, sc);
            r.w = eval_one(v[k].w, sc);
            o4[base + k * TPB] = r;
        }
    } else {
        // guarded tail blocks
#pragma unroll
        for (int k = 0; k < UNROLL; ++k) {
            int i = base + k * TPB;
            if (i < n4) {
                f32x4 v = x4[i];
                f32x4 r;
                r.x = eval_one(v.x, sc);
                r.y = eval_one(v.y, sc);
                r.z = eval_one(v.z, sc);
                r.w = eval_one(v.w, sc);
                o4[i] = r;
            }
        }
    }

    // scalar tail (n not multiple of 4)
    int g = blockIdx.x * TPB + tid;
    int gs = gridDim.x * TPB;
    for (int i = (n4 << 2) + g; i < n; i += gs)
        out[i] = eval_one(x[i], sc);
}

extern "C" void kernel_launch(void* const* d_in, const int* in_sizes, int n_in,
                              void* d_out, int out_size, void* d_ws, size_t ws_size,
                              hipStream_t stream) {
    const float* x  = (const float*)d_in[0];
    const float* cp = (const float*)d_in[1];
    float* out = (float*)d_out;

    int n = in_sizes[0];
    int n4 = n >> 2;
    int per_block = TPB * UNROLL;
    int blocks = (n4 + per_block - 1) / per_block;
    if (blocks < 1) blocks = 1;

    bspline_kernel<<<blocks, TPB, 0, stream>>>(x, cp, out, n);
}

// Round 5
// 25.240 us; speedup vs baseline: 1.0759x; 1.0099x over previous
//
#include <hip/hip_runtime.h>

// B-spline (degree 3, 16 control points, uniform knots linspace(-3,3,20)).
// out(x) = cubic polynomial in u, coefficients per interval j = floor((x+3)/h).
// Zero-padded SoA coef table ctab[4][32]: index jc = clamp(j+1, 0, 20);
// entries 0 and 20 hold zero polynomials, so out-of-range x (x < -3, x >= 3
// incl. ==3) yields 0 without an explicit range check.
// SoA layout: 21 indices <= 32 banks -> every ds_read_b32 is conflict-free
// (distinct index -> distinct bank; same index -> broadcast).

#define N_CP   16
#define NINT   19          // knots = linspace(-3,3,20) -> 19 intervals
#define NTAB   (NINT + 2)  // 21: zero guard entries at both ends
#define TPB    256
#define UNROLL 8

typedef float f32x4 __attribute__((ext_vector_type(4)));

__device__ __forceinline__ float eval_one(float xe, const float (*ctab)[32]) {
    const float inv_h = (float)NINT / 6.0f;
    float t = (xe + 3.0f) * inv_h;                   // knot-index space
    float fj = floorf(t);
    int jc = (int)fj + 1;                            // table index (+1 for guard)
    jc = jc < 0 ? 0 : (jc > NTAB - 1 ? NTAB - 1 : jc);
    float u = t - fj;                                // finite garbage ok on guards
    float a = ctab[0][jc];                           // conflict-free ds_read_b32 x4
    float b = ctab[1][jc];                           // (shared addr + imm offsets)
    float c = ctab[2][jc];
    float d = ctab[3][jc];
    return ((d * u + c) * u + b) * u + a;            // zero coefs -> 0
}

__device__ __forceinline__ void build_coefs(const float* __restrict__ cp,
                                            float (*ctab)[32]) {
    int tid = threadIdx.x;
    if (tid < NTAB) {
        float c0 = 0.0f, c1 = 0.0f, c2 = 0.0f, c3 = 0.0f;
        if (tid >= 1 && tid <= NINT) {
            int j = tid - 1;                          // real interval index
            float p0 = (j - 3 >= 0 && j - 3 < N_CP) ? cp[j - 3] : 0.0f;
            float p1 = (j - 2 >= 0 && j - 2 < N_CP) ? cp[j - 2] : 0.0f;
            float p2 = (j - 1 >= 0 && j - 1 < N_CP) ? cp[j - 1] : 0.0f;
            float p3 = (j     < N_CP)               ? cp[j]     : 0.0f;
            // uniform cubic B-spline basis in powers of u
            c0 = (p0 + 4.0f * p1 + p2) * (1.0f / 6.0f);
            c1 = (p2 - p0) * 0.5f;
            c2 = (p0 - 2.0f * p1 + p2) * 0.5f;
            c3 = (p3 - p0) * (1.0f / 6.0f) + (p1 - p2) * 0.5f;
        }
        ctab[0][tid] = c0;
        ctab[1][tid] = c1;
        ctab[2][tid] = c2;
        ctab[3][tid] = c3;
    }
}

__global__ __launch_bounds__(TPB) void bspline_kernel(
    const float* __restrict__ x,
    const float* __restrict__ cp,
    float* __restrict__ out,
    int n)
{
    __shared__ float ctab[4][32];
    build_coefs(cp, ctab);
    __syncthreads();

    int n4 = n >> 2;
    const f32x4* x4 = (const f32x4*)x;
    f32x4* o4 = (f32x4*)out;

    int tid = threadIdx.x;
    int base = blockIdx.x * (TPB * UNROLL) + tid;

    if (base + (UNROLL - 1) * TPB < n4) {
        // fast path: issue all 8 coalesced 16B loads, then compute+store
        f32x4 v[UNROLL];
#pragma unroll
        for (int k = 0; k < UNROLL; ++k)
            v[k] = x4[base + k * TPB];
#pragma unroll
        for (int k = 0; k < UNROLL; ++k) {
            f32x4 r;
            r.x = eval_one(v[k].x, ctab);
            r.y = eval_one(v[k].y, ctab);
            r.z = eval_one(v[k].z, ctab);
            r.w = eval_one(v[k].w, ctab);
            o4[base + k * TPB] = r;
        }
    } else {
        // guarded tail blocks
#pragma unroll
        for (int k = 0; k < UNROLL; ++k) {
            int i = base + k * TPB;
            if (i < n4) {
                f32x4 v = x4[i];
                f32x4 r;
                r.x = eval_one(v.x, ctab);
                r.y = eval_one(v.y, ctab);
                r.z = eval_one(v.z, ctab);
                r.w = eval_one(v.w, ctab);
                o4[i] = r;
            }
        }
    }

    // scalar tail (n not multiple of 4)
    int g = blockIdx.x * TPB + tid;
    int gs = gridDim.x * TPB;
    for (int i = (n4 << 2) + g; i < n; i += gs)
        out[i] = eval_one(x[i], ctab);
}

extern "C" void kernel_launch(void* const* d_in, const int* in_sizes, int n_in,
                              void* d_out, int out_size, void* d_ws, size_t ws_size,
                              hipStream_t stream) {
    const float* x  = (const float*)d_in[0];
    const float* cp = (const float*)d_in[1];
    float* out = (float*)d_out;

    int n = in_sizes[0];
    int n4 = n >> 2;
    int per_block = TPB * UNROLL;
    int blocks = (n4 + per_block - 1) / per_block;
    if (blocks < 1) blocks = 1;

    bspline_kernel<<<blocks, TPB, 0, stream>>>(x, cp, out, n);
}